// Round 2
// baseline (206.286 us; speedup 1.0000x reference)
//
#include <hip/hip_runtime.h>
#include <hip/hip_bf16.h>

// ---------------------------------------------------------------------------
// MultiHeadSelfAttention (Swin rel-pos bias), B=64 S=196 D=768 H=12 pd=64
// f2b(x) ; wtrans ; bias_pre ; GEMM QKV (dbuf bf16) ; attn (S^T layout) ; GEMM O
// ---------------------------------------------------------------------------

typedef __bf16 bf16x8 __attribute__((ext_vector_type(8)));
typedef __bf16 bf16x4 __attribute__((ext_vector_type(4)));
typedef float  f32x4  __attribute__((ext_vector_type(4)));

#define MROWS 12544      // B*S
#define DDIM  768
#define NHEAD 12
#define SEQ   196
#define KSTR  72         // Ksm row stride (144B, 16B-aligned, quad-balanced)
#define VSTR  232        // Vts / Psm row stride (464B, 16B-aligned, quad-balanced)

static __device__ __forceinline__ f32x4 MFMA(bf16x8 a, bf16x8 b, f32x4 c) {
    return __builtin_amdgcn_mfma_f32_16x16x32_bf16(a, b, c, 0, 0, 0);
}

static __device__ __forceinline__ void gload16(const __bf16* g, __bf16* l) {
    __builtin_amdgcn_global_load_lds(
        (const __attribute__((address_space(1))) void*)(g),
        (__attribute__((address_space(3))) void*)(l),
        16, 0, 0);
}

// ---------------- prep: fp32 -> bf16 (vectorized 8/thread) -----------------
__global__ __launch_bounds__(256) void f2b(const float* __restrict__ in,
                                           __bf16* __restrict__ out) {
    size_t i = ((size_t)blockIdx.x * 256 + threadIdx.x) * 8;
    f32x4 a = *(const f32x4*)&in[i];
    f32x4 b = *(const f32x4*)&in[i + 4];
    bf16x8 o;
    o[0] = (__bf16)a[0]; o[1] = (__bf16)a[1]; o[2] = (__bf16)a[2]; o[3] = (__bf16)a[3];
    o[4] = (__bf16)b[0]; o[5] = (__bf16)b[1]; o[6] = (__bf16)b[2]; o[7] = (__bf16)b[3];
    *(bf16x8*)&out[i] = o;
}

// ---------------- prep: W [k][n] fp32 -> Wt [n][k] bf16 --------------------
__global__ __launch_bounds__(256) void wtrans(const float* __restrict__ W0, const float* __restrict__ W1,
                                              const float* __restrict__ W2, const float* __restrict__ W3,
                                              __bf16* __restrict__ T0, __bf16* __restrict__ T1,
                                              __bf16* __restrict__ T2, __bf16* __restrict__ T3) {
    const float* Ws[4] = {W0, W1, W2, W3};
    __bf16*      Ts[4] = {T0, T1, T2, T3};
    const float* W = Ws[blockIdx.z];
    __bf16*      T = Ts[blockIdx.z];
    __shared__ __bf16 t[32][33];
    int k0 = blockIdx.x * 32, n0 = blockIdx.y * 32;
    int c = threadIdx.x & 31, r = threadIdx.x >> 5;
#pragma unroll
    for (int i = 0; i < 4; ++i)
        t[r + i * 8][c] = (__bf16)W[(size_t)(k0 + r + i * 8) * DDIM + n0 + c];
    __syncthreads();
#pragma unroll
    for (int i = 0; i < 4; ++i)
        T[(size_t)(n0 + r + i * 8) * DDIM + k0 + c] = t[c][r + i * 8];
}

// ---------------- prep: bias[h][q][k] = table[rel[q][k]][h] ----------------
__global__ __launch_bounds__(256) void bias_pre(const float* __restrict__ table,
                                                const int* __restrict__ rel,
                                                float* __restrict__ biasH) {
    int i = blockIdx.x * 256 + threadIdx.x;
    if (i < NHEAD * SEQ * SEQ) {
        int h = i / (SEQ * SEQ), qk = i - h * (SEQ * SEQ);
        biasH[i] = table[rel[qk] * NHEAD + h];
    }
}

// ------- bf16 GEMM, 128x128 tile, BK=32, explicit double-buffer + vmcnt ----
// grid: (N/128, M/128, nz); consecutive blocks share the A-panel (n fastest)
template <typename OutT>
__global__ __launch_bounds__(256) void gemm_bt(const __bf16* __restrict__ A,
                                               const __bf16* __restrict__ Bt0, const __bf16* __restrict__ Bt1,
                                               const __bf16* __restrict__ Bt2,
                                               const float* __restrict__ b0, const float* __restrict__ b1,
                                               const float* __restrict__ b2,
                                               OutT* __restrict__ C0, OutT* __restrict__ C1,
                                               OutT* __restrict__ C2) {
    const __bf16* Bts[3] = {Bt0, Bt1, Bt2};
    const float*  bs[3]  = {b0, b1, b2};
    OutT*         Cs[3]  = {C0, C1, C2};
    const __bf16* Bt = Bts[blockIdx.z];
    const float*  bias = bs[blockIdx.z];
    OutT*         C = Cs[blockIdx.z];

    __shared__ __bf16 Asm[2][128 * 32];
    __shared__ __bf16 Bsm[2][128 * 32];

    const int tid = threadIdx.x, w = tid >> 6, l = tid & 63;
    const int lr = l & 15, lg = l >> 4;
    const int n0 = blockIdx.x * 128, m0 = blockIdx.y * 128;
    const int wr = (w >> 1) * 64, wc = (w & 1) * 64;

    const __bf16* ga = A  + (size_t)(m0 + w * 32 + (l >> 2)) * DDIM + (l & 3) * 8;
    const __bf16* gb = Bt + (size_t)(n0 + w * 32 + (l >> 2)) * DDIM + (l & 3) * 8;

#define STAGE(buf, kt)                                          \
    do {                                                        \
        const int ko_ = (kt) * 32;                              \
        gload16(ga + ko_, &Asm[buf][w * 1024]);                 \
        gload16(ga + ko_ + 16 * DDIM, &Asm[buf][w * 1024 + 512]); \
        gload16(gb + ko_, &Bsm[buf][w * 1024]);                 \
        gload16(gb + ko_ + 16 * DDIM, &Bsm[buf][w * 1024 + 512]); \
    } while (0)

    f32x4 zf = {0.f, 0.f, 0.f, 0.f};
    f32x4 acc[4][4];
#pragma unroll
    for (int i = 0; i < 4; ++i)
#pragma unroll
        for (int j = 0; j < 4; ++j) acc[i][j] = zf;

    STAGE(0, 0);
    const int NT = DDIM / 32;
    for (int kt = 0; kt < NT; ++kt) {
        const int cur = kt & 1;
        if (kt + 1 < NT) {
            STAGE(cur ^ 1, kt + 1);
            asm volatile("s_waitcnt vmcnt(4)" ::: "memory");
        } else {
            asm volatile("s_waitcnt vmcnt(0)" ::: "memory");
        }
        __builtin_amdgcn_s_barrier();
        __builtin_amdgcn_sched_barrier(0);

        bf16x8 af[4], bf_[4];
#pragma unroll
        for (int t = 0; t < 4; ++t)
            af[t] = *(const bf16x8*)&Asm[cur][(wr + t * 16 + lr) * 32 + lg * 8];
#pragma unroll
        for (int t = 0; t < 4; ++t)
            bf_[t] = *(const bf16x8*)&Bsm[cur][(wc + t * 16 + lr) * 32 + lg * 8];
#pragma unroll
        for (int mt = 0; mt < 4; ++mt)
#pragma unroll
            for (int nt = 0; nt < 4; ++nt)
                acc[mt][nt] = MFMA(af[mt], bf_[nt], acc[mt][nt]);

        __builtin_amdgcn_s_barrier();          // readers done before re-stage
        __builtin_amdgcn_sched_barrier(0);
    }
#undef STAGE

#pragma unroll
    for (int nt = 0; nt < 4; ++nt) {
        const int col = n0 + wc + nt * 16 + lr;
        const float bb = bias[col];
#pragma unroll
        for (int mt = 0; mt < 4; ++mt) {
            const int row = m0 + wr + mt * 16 + lg * 4;
#pragma unroll
            for (int r = 0; r < 4; ++r)
                C[(size_t)(row + r) * DDIM + col] = (OutT)(acc[mt][nt][r] + bb);
        }
    }
}

// ---------------- fused attention, S^T layout, 8 waves per (b,h) -----------
__global__ __launch_bounds__(512) void attn_kernel(const __bf16* __restrict__ Qg,
                                                   const __bf16* __restrict__ Kg,
                                                   const __bf16* __restrict__ Vg,
                                                   const float* __restrict__ biasH,
                                                   __bf16* __restrict__ Og) {
    __shared__ __bf16 Ksm[208 * KSTR];         // [208][72]   K rows, zero-padded
    __shared__ __bf16 Vts[64 * VSTR];          // [64][232]   V^T: [d][kk]
    __shared__ __bf16 Psm[8 * 16 * VSTR];      // per-wave [16 q][232 kk]

    const int b = blockIdx.x, h = blockIdx.y;
    const int tid = threadIdx.x, w = tid >> 6, l = tid & 63;
    const int lr = l & 15, lg = l >> 4;
    const size_t base = (size_t)(b * SEQ) * DDIM + h * 64;
    const __bf16* Kb = Kg + base;
    const __bf16* Vb = Vg + base;
    const __bf16* Qb = Qg + base;
    const float*  bh = biasH + (size_t)h * (SEQ * SEQ);

    // stage K rows (16B chunks)
    for (int c = tid; c < SEQ * 8; c += 512) {
        int kk = c >> 3, d8 = (c & 7) << 3;
        *(bf16x8*)&Ksm[kk * KSTR + d8] = *(const bf16x8*)&Kb[(size_t)kk * DDIM + d8];
    }
    // zero K pad rows 196..207 (full 72-col rows)
    for (int c = tid; c < 12 * 9; c += 512) {
        int kk = SEQ + c / 9, d8 = (c % 9) * 8;
        *(uint4*)&Ksm[kk * KSTR + d8] = make_uint4(0u, 0u, 0u, 0u);
    }
    // stage V transposed
    for (int c = tid; c < SEQ * 8; c += 512) {
        int kk = c >> 3, d8 = (c & 7) << 3;
        bf16x8 vv = *(const bf16x8*)&Vb[(size_t)kk * DDIM + d8];
#pragma unroll
        for (int j = 0; j < 8; ++j) Vts[(d8 + j) * VSTR + kk] = vv[j];
    }
    // zero Vt cols 196..223
    for (int c = tid; c < 64 * 28; c += 512)
        Vts[(c / 28) * VSTR + SEQ + (c % 28)] = (__bf16)0.f;
    // zero own-wave P cols 208..223
    __bf16* Pw = &Psm[w * 16 * VSTR];
    for (int c = l; c < 256; c += 64)
        Pw[(c >> 4) * VSTR + 208 + (c & 15)] = (__bf16)0.f;
    __syncthreads();

    for (int qt = w; qt < 13; qt += 8) {
        const int q0 = qt * 16;
        const int q = q0 + lr;                 // this lane's query row
        const int qrow = min(q, SEQ - 1);
        // Q B-fragment: Q[q][d], d = lg*8..+7 and +32
        bf16x8 bq0 = *(const bf16x8*)&Qb[(size_t)qrow * DDIM + lg * 8];
        bf16x8 bq1 = *(const bf16x8*)&Qb[(size_t)qrow * DDIM + 32 + lg * 8];

        // S^T tiles: sc[t][r] = S[kk = t*16 + lg*4 + r][q]
        f32x4 sc[13];
#pragma unroll
        for (int t = 0; t < 13; ++t) {
            bf16x8 kf0 = *(const bf16x8*)&Ksm[(t * 16 + lr) * KSTR + lg * 8];
            bf16x8 kf1 = *(const bf16x8*)&Ksm[(t * 16 + lr) * KSTR + 32 + lg * 8];
            f32x4 a = {0.f, 0.f, 0.f, 0.f};
            a = MFMA(kf0, bq0, a);
            a = MFMA(kf1, bq1, a);
            sc[t] = a;
        }

        // scale + bias + mask; lane-local row max
        float mx = -1e30f;
#pragma unroll
        for (int t = 0; t < 13; ++t) {
            const bool val4 = (t < 12) || (lg == 0);   // kk block fully < 196
            f32x4 bb = {0.f, 0.f, 0.f, 0.f};
            if (val4) bb = *(const f32x4*)&bh[(size_t)qrow * SEQ + t * 16 + lg * 4];
#pragma unroll
            for (int r = 0; r < 4; ++r) {
                float v = val4 ? (sc[t][r] * 0.125f + bb[r]) : -1e30f;
                sc[t][r] = v;
                mx = fmaxf(mx, v);
            }
        }
        mx = fmaxf(mx, __shfl_xor(mx, 16));
        mx = fmaxf(mx, __shfl_xor(mx, 32));

        float sum = 0.f;
#pragma unroll
        for (int t = 0; t < 13; ++t)
#pragma unroll
            for (int r = 0; r < 4; ++r) {
                float p = __expf(sc[t][r] - mx);
                sum += p;
                sc[t][r] = p;
            }
        sum += __shfl_xor(sum, 16);
        sum += __shfl_xor(sum, 32);
        const float inv = 1.f / sum;

        // write P row q (bf16, packed 8B): cols t*16 + lg*4 .. +3
#pragma unroll
        for (int t = 0; t < 13; ++t) {
            bf16x4 pk;
#pragma unroll
            for (int r = 0; r < 4; ++r) pk[r] = (__bf16)sc[t][r];
            *(bf16x4*)&Pw[lr * VSTR + t * 16 + lg * 4] = pk;
        }

        // PV: out^T[d][q] += V^T[d][kk] * P[q][kk]
        f32x4 oa[4];
#pragma unroll
        for (int i = 0; i < 4; ++i) oa[i] = (f32x4){0.f, 0.f, 0.f, 0.f};
#pragma unroll
        for (int kt = 0; kt < 7; ++kt) {
            bf16x8 pf = *(const bf16x8*)&Pw[lr * VSTR + kt * 32 + lg * 8];
#pragma unroll
            for (int nt = 0; nt < 4; ++nt) {
                bf16x8 vf = *(const bf16x8*)&Vts[(nt * 16 + lr) * VSTR + kt * 32 + lg * 8];
                oa[nt] = MFMA(vf, pf, oa[nt]);
            }
        }

        if (q < SEQ) {
#pragma unroll
            for (int nt = 0; nt < 4; ++nt) {
                bf16x4 ok;
#pragma unroll
                for (int r = 0; r < 4; ++r) ok[r] = (__bf16)(oa[nt][r] * inv);
                *(bf16x4*)&Og[(size_t)(b * SEQ + q) * DDIM + h * 64 + nt * 16 + lg * 4] = ok;
            }
        }
    }
}

// ---------------------------------------------------------------------------
extern "C" void kernel_launch(void* const* d_in, const int* in_sizes, int n_in,
                              void* d_out, int out_size, void* d_ws, size_t ws_size,
                              hipStream_t stream) {
    const float* x     = (const float*)d_in[0];
    const float* Wq    = (const float*)d_in[1];
    const float* bq    = (const float*)d_in[2];
    const float* Wk    = (const float*)d_in[3];
    const float* bk    = (const float*)d_in[4];
    const float* Wv    = (const float*)d_in[5];
    const float* bv    = (const float*)d_in[6];
    const float* Wo    = (const float*)d_in[7];
    const float* bo    = (const float*)d_in[8];
    const float* table = (const float*)d_in[9];
    const int*   rel   = (const int*)d_in[10];
    float* out = (float*)d_out;

    char* ws = (char*)d_ws;
    auto alloc = [&](size_t bytes) {
        char* p = ws;
        ws += (bytes + 255) & ~(size_t)255;
        return p;
    };
    const size_t mat = (size_t)MROWS * DDIM * sizeof(__bf16);
    __bf16* xb = (__bf16*)alloc(mat);
    __bf16* Tq = (__bf16*)alloc((size_t)DDIM * DDIM * 2);
    __bf16* Tk = (__bf16*)alloc((size_t)DDIM * DDIM * 2);
    __bf16* Tv = (__bf16*)alloc((size_t)DDIM * DDIM * 2);
    __bf16* To = (__bf16*)alloc((size_t)DDIM * DDIM * 2);
    __bf16* Qb = (__bf16*)alloc(mat);
    __bf16* Kb = (__bf16*)alloc(mat);
    __bf16* Vb = (__bf16*)alloc(mat);
    __bf16* AO = (__bf16*)alloc(mat);
    float* biasH = (float*)alloc((size_t)NHEAD * SEQ * SEQ * 4);

    f2b<<<dim3(4704), 256, 0, stream>>>(x, xb);
    wtrans<<<dim3(24, 24, 4), 256, 0, stream>>>(Wq, Wk, Wv, Wo, Tq, Tk, Tv, To);
    bias_pre<<<dim3(1801), 256, 0, stream>>>(table, rel, biasH);
    gemm_bt<__bf16><<<dim3(6, 98, 3), 256, 0, stream>>>(xb, Tq, Tk, Tv, bq, bk, bv, Qb, Kb, Vb);
    attn_kernel<<<dim3(64, 12), 512, 0, stream>>>(Qb, Kb, Vb, biasH, AO);
    gemm_bt<float><<<dim3(6, 98, 1), 256, 0, stream>>>(AO, To, To, To, bo, bo, bo, out, out, out);
}

// Round 3
// 191.589 us; speedup vs baseline: 1.0767x; 1.0767x over previous
//
#include <hip/hip_runtime.h>
#include <hip/hip_bf16.h>

// ---------------------------------------------------------------------------
// MultiHeadSelfAttention (Swin rel-pos bias), B=64 S=196 D=768 H=12 pd=64
// f2b(x) ; wtrans ; bias_pre(bf16) ; GEMM QKV (dbuf) ; attn (S^T, 512thr, no-spill) ; GEMM O
// ---------------------------------------------------------------------------

typedef __bf16 bf16x8 __attribute__((ext_vector_type(8)));
typedef __bf16 bf16x4 __attribute__((ext_vector_type(4)));
typedef float  f32x4  __attribute__((ext_vector_type(4)));

#define MROWS 12544      // B*S
#define DDIM  768
#define NHEAD 12
#define SEQ   196
#define KSTR  72         // Ksm row stride (144B, 16B-aligned, quad-balanced)
#define VSTR  232        // Vts / Psm row stride (464B, 16B-aligned, quad-balanced)

static __device__ __forceinline__ f32x4 MFMA(bf16x8 a, bf16x8 b, f32x4 c) {
    return __builtin_amdgcn_mfma_f32_16x16x32_bf16(a, b, c, 0, 0, 0);
}

static __device__ __forceinline__ void gload16(const __bf16* g, __bf16* l) {
    __builtin_amdgcn_global_load_lds(
        (const __attribute__((address_space(1))) void*)(g),
        (__attribute__((address_space(3))) void*)(l),
        16, 0, 0);
}

// ---------------- prep: fp32 -> bf16 (vectorized 8/thread) -----------------
__global__ __launch_bounds__(256) void f2b(const float* __restrict__ in,
                                           __bf16* __restrict__ out) {
    size_t i = ((size_t)blockIdx.x * 256 + threadIdx.x) * 8;
    f32x4 a = *(const f32x4*)&in[i];
    f32x4 b = *(const f32x4*)&in[i + 4];
    bf16x8 o;
    o[0] = (__bf16)a[0]; o[1] = (__bf16)a[1]; o[2] = (__bf16)a[2]; o[3] = (__bf16)a[3];
    o[4] = (__bf16)b[0]; o[5] = (__bf16)b[1]; o[6] = (__bf16)b[2]; o[7] = (__bf16)b[3];
    *(bf16x8*)&out[i] = o;
}

// ---------------- prep: W [k][n] fp32 -> Wt [n][k] bf16 --------------------
__global__ __launch_bounds__(256) void wtrans(const float* __restrict__ W0, const float* __restrict__ W1,
                                              const float* __restrict__ W2, const float* __restrict__ W3,
                                              __bf16* __restrict__ T0, __bf16* __restrict__ T1,
                                              __bf16* __restrict__ T2, __bf16* __restrict__ T3) {
    const float* Ws[4] = {W0, W1, W2, W3};
    __bf16*      Ts[4] = {T0, T1, T2, T3};
    const float* W = Ws[blockIdx.z];
    __bf16*      T = Ts[blockIdx.z];
    __shared__ __bf16 t[32][33];
    int k0 = blockIdx.x * 32, n0 = blockIdx.y * 32;
    int c = threadIdx.x & 31, r = threadIdx.x >> 5;
#pragma unroll
    for (int i = 0; i < 4; ++i)
        t[r + i * 8][c] = (__bf16)W[(size_t)(k0 + r + i * 8) * DDIM + n0 + c];
    __syncthreads();
#pragma unroll
    for (int i = 0; i < 4; ++i)
        T[(size_t)(n0 + r + i * 8) * DDIM + k0 + c] = t[c][r + i * 8];
}

// ---------------- prep: bias[h][q][k] = table[rel[q][k]][h]  (bf16) --------
__global__ __launch_bounds__(256) void bias_pre(const float* __restrict__ table,
                                                const int* __restrict__ rel,
                                                __bf16* __restrict__ biasH) {
    int i = blockIdx.x * 256 + threadIdx.x;
    if (i < NHEAD * SEQ * SEQ) {
        int h = i / (SEQ * SEQ), qk = i - h * (SEQ * SEQ);
        biasH[i] = (__bf16)table[rel[qk] * NHEAD + h];
    }
}

// ------- bf16 GEMM, 128x128 tile, BK=32, explicit double-buffer + vmcnt ----
// grid: (N/128, M/128, nz); consecutive blocks share the A-panel (n fastest)
template <typename OutT>
__global__ __launch_bounds__(256) void gemm_bt(const __bf16* __restrict__ A,
                                               const __bf16* __restrict__ Bt0, const __bf16* __restrict__ Bt1,
                                               const __bf16* __restrict__ Bt2,
                                               const float* __restrict__ b0, const float* __restrict__ b1,
                                               const float* __restrict__ b2,
                                               OutT* __restrict__ C0, OutT* __restrict__ C1,
                                               OutT* __restrict__ C2) {
    const __bf16* Bts[3] = {Bt0, Bt1, Bt2};
    const float*  bs[3]  = {b0, b1, b2};
    OutT*         Cs[3]  = {C0, C1, C2};
    const __bf16* Bt = Bts[blockIdx.z];
    const float*  bias = bs[blockIdx.z];
    OutT*         C = Cs[blockIdx.z];

    __shared__ __bf16 Asm[2][128 * 32];
    __shared__ __bf16 Bsm[2][128 * 32];

    const int tid = threadIdx.x, w = tid >> 6, l = tid & 63;
    const int lr = l & 15, lg = l >> 4;
    const int n0 = blockIdx.x * 128, m0 = blockIdx.y * 128;
    const int wr = (w >> 1) * 64, wc = (w & 1) * 64;

    const __bf16* ga = A  + (size_t)(m0 + w * 32 + (l >> 2)) * DDIM + (l & 3) * 8;
    const __bf16* gb = Bt + (size_t)(n0 + w * 32 + (l >> 2)) * DDIM + (l & 3) * 8;

#define STAGE(buf, kt)                                          \
    do {                                                        \
        const int ko_ = (kt) * 32;                              \
        gload16(ga + ko_, &Asm[buf][w * 1024]);                 \
        gload16(ga + ko_ + 16 * DDIM, &Asm[buf][w * 1024 + 512]); \
        gload16(gb + ko_, &Bsm[buf][w * 1024]);                 \
        gload16(gb + ko_ + 16 * DDIM, &Bsm[buf][w * 1024 + 512]); \
    } while (0)

    f32x4 zf = {0.f, 0.f, 0.f, 0.f};
    f32x4 acc[4][4];
#pragma unroll
    for (int i = 0; i < 4; ++i)
#pragma unroll
        for (int j = 0; j < 4; ++j) acc[i][j] = zf;

    STAGE(0, 0);
    const int NT = DDIM / 32;
    for (int kt = 0; kt < NT; ++kt) {
        const int cur = kt & 1;
        if (kt + 1 < NT) {
            STAGE(cur ^ 1, kt + 1);
            asm volatile("s_waitcnt vmcnt(4)" ::: "memory");
        } else {
            asm volatile("s_waitcnt vmcnt(0)" ::: "memory");
        }
        __builtin_amdgcn_s_barrier();
        __builtin_amdgcn_sched_barrier(0);

        bf16x8 af[4], bf_[4];
#pragma unroll
        for (int t = 0; t < 4; ++t)
            af[t] = *(const bf16x8*)&Asm[cur][(wr + t * 16 + lr) * 32 + lg * 8];
#pragma unroll
        for (int t = 0; t < 4; ++t)
            bf_[t] = *(const bf16x8*)&Bsm[cur][(wc + t * 16 + lr) * 32 + lg * 8];
#pragma unroll
        for (int mt = 0; mt < 4; ++mt)
#pragma unroll
            for (int nt = 0; nt < 4; ++nt)
                acc[mt][nt] = MFMA(af[mt], bf_[nt], acc[mt][nt]);

        __builtin_amdgcn_s_barrier();          // readers done before re-stage
        __builtin_amdgcn_sched_barrier(0);
    }
#undef STAGE

#pragma unroll
    for (int nt = 0; nt < 4; ++nt) {
        const int col = n0 + wc + nt * 16 + lr;
        const float bb = bias[col];
#pragma unroll
        for (int mt = 0; mt < 4; ++mt) {
            const int row = m0 + wr + mt * 16 + lg * 4;
#pragma unroll
            for (int r = 0; r < 4; ++r)
                C[(size_t)(row + r) * DDIM + col] = (OutT)(acc[mt][nt][r] + bb);
        }
    }
}

// ---------------- fused attention, S^T layout, 8 waves per (b,h) -----------
// __launch_bounds__(512, 2): 2 waves/EU -> 256-VGPR budget, NO SPILL.
__global__ __launch_bounds__(512, 2) void attn_kernel(const __bf16* __restrict__ Qg,
                                                      const __bf16* __restrict__ Kg,
                                                      const __bf16* __restrict__ Vg,
                                                      const __bf16* __restrict__ biasH,
                                                      __bf16* __restrict__ Og) {
    __shared__ __bf16 Ksm[208 * KSTR];         // [208][72]   K rows, zero-padded
    __shared__ __bf16 Vts[64 * VSTR];          // [64][232]   V^T: [d][kk]
    __shared__ __bf16 Psm[8 * 16 * VSTR];      // per-wave [16 q][232 kk]

    const int b = blockIdx.x, h = blockIdx.y;
    const int tid = threadIdx.x, w = tid >> 6, l = tid & 63;
    const int lr = l & 15, lg = l >> 4;
    const size_t base = (size_t)(b * SEQ) * DDIM + h * 64;
    const __bf16* Kb = Kg + base;
    const __bf16* Vb = Vg + base;
    const __bf16* Qb = Qg + base;
    const __bf16* bh = biasH + (size_t)h * (SEQ * SEQ);

    // stage K rows (16B chunks)
    for (int c = tid; c < SEQ * 8; c += 512) {
        int kk = c >> 3, d8 = (c & 7) << 3;
        *(bf16x8*)&Ksm[kk * KSTR + d8] = *(const bf16x8*)&Kb[(size_t)kk * DDIM + d8];
    }
    // zero K pad rows 196..207 (full 72-col rows)
    for (int c = tid; c < 12 * 9; c += 512) {
        int kk = SEQ + c / 9, d8 = (c % 9) * 8;
        *(uint4*)&Ksm[kk * KSTR + d8] = make_uint4(0u, 0u, 0u, 0u);
    }
    // stage V transposed
    for (int c = tid; c < SEQ * 8; c += 512) {
        int kk = c >> 3, d8 = (c & 7) << 3;
        bf16x8 vv = *(const bf16x8*)&Vb[(size_t)kk * DDIM + d8];
#pragma unroll
        for (int j = 0; j < 8; ++j) Vts[(d8 + j) * VSTR + kk] = vv[j];
    }
    // zero Vt cols 196..223
    for (int c = tid; c < 64 * 28; c += 512)
        Vts[(c / 28) * VSTR + SEQ + (c % 28)] = (__bf16)0.f;
    // zero own-wave P cols 208..223
    __bf16* Pw = &Psm[w * 16 * VSTR];
    for (int c = l; c < 256; c += 64)
        Pw[(c >> 4) * VSTR + 208 + (c & 15)] = (__bf16)0.f;
    __syncthreads();

    for (int qt = w; qt < 13; qt += 8) {
        const int q0 = qt * 16;
        const int q = q0 + lr;                 // this lane's query row
        const int qrow = min(q, SEQ - 1);
        // Q B-fragment: Q[q][d], d = lg*8..+7 and +32
        bf16x8 bq0 = *(const bf16x8*)&Qb[(size_t)qrow * DDIM + lg * 8];
        bf16x8 bq1 = *(const bf16x8*)&Qb[(size_t)qrow * DDIM + 32 + lg * 8];

        // S^T tiles: sc[t][r] = S[kk = t*16 + lg*4 + r][q]
        f32x4 sc[13];
#pragma unroll
        for (int t = 0; t < 13; ++t) {
            bf16x8 kf0 = *(const bf16x8*)&Ksm[(t * 16 + lr) * KSTR + lg * 8];
            bf16x8 kf1 = *(const bf16x8*)&Ksm[(t * 16 + lr) * KSTR + 32 + lg * 8];
            f32x4 a = {0.f, 0.f, 0.f, 0.f};
            a = MFMA(kf0, bq0, a);
            a = MFMA(kf1, bq1, a);
            sc[t] = a;
        }

        // scale + bias + mask; lane-local row max
        float mx = -1e30f;
#pragma unroll
        for (int t = 0; t < 13; ++t) {
            const bool val4 = (t < 12) || (lg == 0);   // kk block fully < 196
            float bb[4] = {0.f, 0.f, 0.f, 0.f};
            if (val4) {
                bf16x4 b4 = *(const bf16x4*)&bh[(size_t)qrow * SEQ + t * 16 + lg * 4];
#pragma unroll
                for (int r = 0; r < 4; ++r) bb[r] = (float)b4[r];
            }
#pragma unroll
            for (int r = 0; r < 4; ++r) {
                float v = val4 ? (sc[t][r] * 0.125f + bb[r]) : -1e30f;
                sc[t][r] = v;
                mx = fmaxf(mx, v);
            }
        }
        mx = fmaxf(mx, __shfl_xor(mx, 16));
        mx = fmaxf(mx, __shfl_xor(mx, 32));

        float sum = 0.f;
#pragma unroll
        for (int t = 0; t < 13; ++t)
#pragma unroll
            for (int r = 0; r < 4; ++r) {
                float p = __expf(sc[t][r] - mx);
                sum += p;
                sc[t][r] = p;
            }
        sum += __shfl_xor(sum, 16);
        sum += __shfl_xor(sum, 32);
        const float inv = 1.f / sum;

        // write P row q (bf16, packed 8B): cols t*16 + lg*4 .. +3
#pragma unroll
        for (int t = 0; t < 13; ++t) {
            bf16x4 pk;
#pragma unroll
            for (int r = 0; r < 4; ++r) pk[r] = (__bf16)sc[t][r];
            *(bf16x4*)&Pw[lr * VSTR + t * 16 + lg * 4] = pk;
        }

        // PV: out^T[d][q] += V^T[d][kk] * P[q][kk]
        f32x4 oa[4];
#pragma unroll
        for (int i = 0; i < 4; ++i) oa[i] = (f32x4){0.f, 0.f, 0.f, 0.f};
#pragma unroll
        for (int kt = 0; kt < 7; ++kt) {
            bf16x8 pf = *(const bf16x8*)&Pw[lr * VSTR + kt * 32 + lg * 8];
#pragma unroll
            for (int nt = 0; nt < 4; ++nt) {
                bf16x8 vf = *(const bf16x8*)&Vts[(nt * 16 + lr) * VSTR + kt * 32 + lg * 8];
                oa[nt] = MFMA(vf, pf, oa[nt]);
            }
        }

        if (q < SEQ) {
#pragma unroll
            for (int nt = 0; nt < 4; ++nt) {
                bf16x4 ok;
#pragma unroll
                for (int r = 0; r < 4; ++r) ok[r] = (__bf16)(oa[nt][r] * inv);
                *(bf16x4*)&Og[(size_t)(b * SEQ + q) * DDIM + h * 64 + nt * 16 + lg * 4] = ok;
            }
        }
    }
}

// ---------------------------------------------------------------------------
extern "C" void kernel_launch(void* const* d_in, const int* in_sizes, int n_in,
                              void* d_out, int out_size, void* d_ws, size_t ws_size,
                              hipStream_t stream) {
    const float* x     = (const float*)d_in[0];
    const float* Wq    = (const float*)d_in[1];
    const float* bq    = (const float*)d_in[2];
    const float* Wk    = (const float*)d_in[3];
    const float* bk    = (const float*)d_in[4];
    const float* Wv    = (const float*)d_in[5];
    const float* bv    = (const float*)d_in[6];
    const float* Wo    = (const float*)d_in[7];
    const float* bo    = (const float*)d_in[8];
    const float* table = (const float*)d_in[9];
    const int*   rel   = (const int*)d_in[10];
    float* out = (float*)d_out;

    char* ws = (char*)d_ws;
    auto alloc = [&](size_t bytes) {
        char* p = ws;
        ws += (bytes + 255) & ~(size_t)255;
        return p;
    };
    const size_t mat = (size_t)MROWS * DDIM * sizeof(__bf16);
    __bf16* xb = (__bf16*)alloc(mat);
    __bf16* Tq = (__bf16*)alloc((size_t)DDIM * DDIM * 2);
    __bf16* Tk = (__bf16*)alloc((size_t)DDIM * DDIM * 2);
    __bf16* Tv = (__bf16*)alloc((size_t)DDIM * DDIM * 2);
    __bf16* To = (__bf16*)alloc((size_t)DDIM * DDIM * 2);
    __bf16* Qb = (__bf16*)alloc(mat);
    __bf16* Kb = (__bf16*)alloc(mat);
    __bf16* Vb = (__bf16*)alloc(mat);
    __bf16* AO = (__bf16*)alloc(mat);
    __bf16* biasH = (__bf16*)alloc((size_t)NHEAD * SEQ * SEQ * 2);

    f2b<<<dim3(4704), 256, 0, stream>>>(x, xb);
    wtrans<<<dim3(24, 24, 4), 256, 0, stream>>>(Wq, Wk, Wv, Wo, Tq, Tk, Tv, To);
    bias_pre<<<dim3(1801), 256, 0, stream>>>(table, rel, biasH);
    gemm_bt<__bf16><<<dim3(6, 98, 3), 256, 0, stream>>>(xb, Tq, Tk, Tv, bq, bk, bv, Qb, Kb, Vb);
    attn_kernel<<<dim3(64, 12), 512, 0, stream>>>(Qb, Kb, Vb, biasH, AO);
    gemm_bt<float><<<dim3(6, 98, 1), 256, 0, stream>>>(AO, To, To, To, bo, bo, bo, out, out, out);
}

// Round 4
// 171.839 us; speedup vs baseline: 1.2005x; 1.1149x over previous
//
#include <hip/hip_runtime.h>
#include <hip/hip_bf16.h>

// ---------------------------------------------------------------------------
// MultiHeadSelfAttention (Swin rel-pos bias), B=64 S=196 D=768 H=12 pd=64
// f2b ; wtrans(stacked) ; bias_pre(bf16) ; gemm8p QKV (256^2 8-phase) ;
// attn (S^T, setprio) ; gemm8p O-proj
// ---------------------------------------------------------------------------

typedef __bf16 bf16x8 __attribute__((ext_vector_type(8)));
typedef __bf16 bf16x4 __attribute__((ext_vector_type(4)));
typedef float  f32x4  __attribute__((ext_vector_type(4)));

#define MROWS 12544
#define DDIM  768
#define NHEAD 12
#define SEQ   196
#define KSTR  72
#define VSTR  232

static __device__ __forceinline__ f32x4 MFMA(bf16x8 a, bf16x8 b, f32x4 c) {
    return __builtin_amdgcn_mfma_f32_16x16x32_bf16(a, b, c, 0, 0, 0);
}

static __device__ __forceinline__ void gload16(const __bf16* g, __bf16* l) {
    __builtin_amdgcn_global_load_lds(
        (const __attribute__((address_space(1))) void*)(g),
        (__attribute__((address_space(3))) void*)(l),
        16, 0, 0);
}

// ---------------- prep: fp32 -> bf16 ---------------------------------------
__global__ __launch_bounds__(256) void f2b(const float* __restrict__ in,
                                           __bf16* __restrict__ out) {
    size_t i = ((size_t)blockIdx.x * 256 + threadIdx.x) * 8;
    f32x4 a = *(const f32x4*)&in[i];
    f32x4 b = *(const f32x4*)&in[i + 4];
    bf16x8 o;
    o[0] = (__bf16)a[0]; o[1] = (__bf16)a[1]; o[2] = (__bf16)a[2]; o[3] = (__bf16)a[3];
    o[4] = (__bf16)b[0]; o[5] = (__bf16)b[1]; o[6] = (__bf16)b[2]; o[7] = (__bf16)b[3];
    *(bf16x8*)&out[i] = o;
}

// ---------------- prep: W [k][n] fp32 -> Wt [n][k] bf16 --------------------
__global__ __launch_bounds__(256) void wtrans(const float* __restrict__ W0, const float* __restrict__ W1,
                                              const float* __restrict__ W2, const float* __restrict__ W3,
                                              __bf16* __restrict__ T0, __bf16* __restrict__ T1,
                                              __bf16* __restrict__ T2, __bf16* __restrict__ T3) {
    const float* Ws[4] = {W0, W1, W2, W3};
    __bf16*      Ts[4] = {T0, T1, T2, T3};
    const float* W = Ws[blockIdx.z];
    __bf16*      T = Ts[blockIdx.z];
    __shared__ __bf16 t[32][33];
    int k0 = blockIdx.x * 32, n0 = blockIdx.y * 32;
    int c = threadIdx.x & 31, r = threadIdx.x >> 5;
#pragma unroll
    for (int i = 0; i < 4; ++i)
        t[r + i * 8][c] = (__bf16)W[(size_t)(k0 + r + i * 8) * DDIM + n0 + c];
    __syncthreads();
#pragma unroll
    for (int i = 0; i < 4; ++i)
        T[(size_t)(n0 + r + i * 8) * DDIM + k0 + c] = t[c][r + i * 8];
}

// ---------------- prep: bias[h][q][k] = table[rel[q][k]][h]  (bf16) --------
__global__ __launch_bounds__(256) void bias_pre(const float* __restrict__ table,
                                                const int* __restrict__ rel,
                                                __bf16* __restrict__ biasH) {
    int i = blockIdx.x * 256 + threadIdx.x;
    if (i < NHEAD * SEQ * SEQ) {
        int h = i / (SEQ * SEQ), qk = i - h * (SEQ * SEQ);
        biasH[i] = (__bf16)table[rel[qk] * NHEAD + h];
    }
}

// ---------------------------------------------------------------------------
// 256x256 8-phase GEMM: C = A[M][768] * Bt[N][768]^T + bias
// 8 waves (2m x 4n), BK=64, A triple-buffered, B double-buffered (160 KiB),
// LDS XOR swizzle (col16 ^= row&7) via pre-swizzled global source,
// counted vmcnt(8) gates at p3/p7 only. NMAT: outputs routed by n/768.
// ---------------------------------------------------------------------------
template <typename OutT, int NMAT>
__global__ __launch_bounds__(512, 2) void gemm8p(const __bf16* __restrict__ A,
                                                 const __bf16* __restrict__ Bt,
                                                 const float* __restrict__ bz0,
                                                 const float* __restrict__ bz1,
                                                 const float* __restrict__ bz2,
                                                 OutT* __restrict__ Cz0,
                                                 OutT* __restrict__ Cz1,
                                                 OutT* __restrict__ Cz2,
                                                 int nbn) {
    __shared__ __bf16 As[3][256 * 64];   // 3 x 32 KiB
    __shared__ __bf16 Bs[2][256 * 64];   // 2 x 32 KiB

    // bijective XCD-aware swizzle (m204)
    const int nwg = gridDim.x, orig = blockIdx.x;
    const int qq = nwg >> 3, r8 = nwg & 7, xcd = orig & 7, lin = orig >> 3;
    const int wg = (xcd < r8 ? xcd * (qq + 1) : r8 * (qq + 1) + (xcd - r8) * qq) + lin;
    const int bm = wg / nbn, bn = wg - bm * nbn;
    const int m0 = bm * 256, n0g = bn * 256;

    const int tid = threadIdx.x, w = tid >> 6, l = tid & 63;
    const int lr = l & 15, lg = l >> 4;
    const int wrow = (w >> 2) * 128;     // 0 / 128
    const int wcol = (w & 3) * 64;       // 0 / 64 / 128 / 192

    // staging source (pre-swizzled column so linear LDS holds swizzled layout)
    const int srow = w * 8 + (l >> 3);                    // 0..63
    const int scol = ((l & 7) ^ ((l >> 3) & 7)) * 8;      // inverse-swz source col
    const __bf16* gA = A  + (size_t)(m0 + srow) * DDIM + scol;
    const __bf16* gB = Bt + (size_t)(n0g + srow) * DDIM + scol;

#define STAGE_A(slot, h, kt)                                                      \
    do {                                                                          \
        gload16(gA + ((h) * 128 + 0) * DDIM + (kt) * 64,                          \
                &As[slot][(h) * 8192 + 0 + w * 512]);                             \
        gload16(gA + ((h) * 128 + 64) * DDIM + (kt) * 64,                         \
                &As[slot][(h) * 8192 + 4096 + w * 512]);                          \
    } while (0)
#define STAGE_B(slot, h, kt)                                                      \
    do {                                                                          \
        gload16(gB + ((h) * 128 + 0) * DDIM + (kt) * 64,                          \
                &Bs[slot][(h) * 8192 + 0 + w * 512]);                             \
        gload16(gB + ((h) * 128 + 64) * DDIM + (kt) * 64,                         \
                &Bs[slot][(h) * 8192 + 4096 + w * 512]);                          \
    } while (0)

    // swizzled fragment reads (row&7 == lr&7 for all our rows)
#define AF(slot, mf, ks)                                                          \
    (*(const bf16x8*)&As[slot][(w >> 2) * 8192 + ((mf) * 16 + lr) * 64 +          \
                              ((((ks) * 4 + lg) ^ (lr & 7))) * 8])
#define BF(slot, nf, ks)                                                          \
    (*(const bf16x8*)&Bs[slot][((w & 3) >> 1) * 8192 +                            \
                              ((w & 1) * 64 + (nf) * 16 + lr) * 64 +              \
                              ((((ks) * 4 + lg) ^ (lr & 7))) * 8])

    f32x4 acc[8][4];
#pragma unroll
    for (int i = 0; i < 8; ++i)
#pragma unroll
        for (int j = 0; j < 4; ++j) acc[i][j] = (f32x4){0.f, 0.f, 0.f, 0.f};

    bf16x8 a0, a1, a2, a3;
    bf16x8 bfr00, bfr01, bfr10, bfr11, bfr20, bfr21, bfr30, bfr31;

#define DSLOAD_A(slot, mf0)                                                       \
    a0 = AF(slot, mf0, 0); a1 = AF(slot, mf0, 1);                                 \
    a2 = AF(slot, (mf0) + 1, 0); a3 = AF(slot, (mf0) + 1, 1);
#define DSLOAD_B(slot)                                                            \
    bfr00 = BF(slot, 0, 0); bfr01 = BF(slot, 0, 1);                               \
    bfr10 = BF(slot, 1, 0); bfr11 = BF(slot, 1, 1);                               \
    bfr20 = BF(slot, 2, 0); bfr21 = BF(slot, 2, 1);                               \
    bfr30 = BF(slot, 3, 0); bfr31 = BF(slot, 3, 1);
#define BARRIER_IN()                                                              \
    __builtin_amdgcn_sched_barrier(0);                                            \
    __builtin_amdgcn_s_barrier();                                                 \
    asm volatile("s_waitcnt lgkmcnt(0)" ::: "memory");                            \
    __builtin_amdgcn_sched_barrier(0);                                            \
    __builtin_amdgcn_s_setprio(1);
#define BARRIER_OUT()                                                             \
    __builtin_amdgcn_s_setprio(0);                                                \
    __builtin_amdgcn_sched_barrier(0);                                            \
    __builtin_amdgcn_s_barrier();                                                 \
    __builtin_amdgcn_sched_barrier(0);
#define MFMACL(mf0)                                                               \
    acc[mf0][0] = MFMA(a0, bfr00, acc[mf0][0]);                                   \
    acc[mf0][0] = MFMA(a1, bfr01, acc[mf0][0]);                                   \
    acc[(mf0) + 1][0] = MFMA(a2, bfr00, acc[(mf0) + 1][0]);                       \
    acc[(mf0) + 1][0] = MFMA(a3, bfr01, acc[(mf0) + 1][0]);                       \
    acc[mf0][1] = MFMA(a0, bfr10, acc[mf0][1]);                                   \
    acc[mf0][1] = MFMA(a1, bfr11, acc[mf0][1]);                                   \
    acc[(mf0) + 1][1] = MFMA(a2, bfr10, acc[(mf0) + 1][1]);                       \
    acc[(mf0) + 1][1] = MFMA(a3, bfr11, acc[(mf0) + 1][1]);                       \
    acc[mf0][2] = MFMA(a0, bfr20, acc[mf0][2]);                                   \
    acc[mf0][2] = MFMA(a1, bfr21, acc[mf0][2]);                                   \
    acc[(mf0) + 1][2] = MFMA(a2, bfr20, acc[(mf0) + 1][2]);                       \
    acc[(mf0) + 1][2] = MFMA(a3, bfr21, acc[(mf0) + 1][2]);                       \
    acc[mf0][3] = MFMA(a0, bfr30, acc[mf0][3]);                                   \
    acc[mf0][3] = MFMA(a1, bfr31, acc[mf0][3]);                                   \
    acc[(mf0) + 1][3] = MFMA(a2, bfr30, acc[(mf0) + 1][3]);                       \
    acc[(mf0) + 1][3] = MFMA(a3, bfr31, acc[(mf0) + 1][3]);

    // prologue: K0 -> As[0]/Bs[0], K1 -> As[1]/Bs[1]
    STAGE_A(0, 0, 0); STAGE_A(0, 1, 0); STAGE_B(0, 0, 0); STAGE_B(0, 1, 0);
    STAGE_A(1, 0, 1); STAGE_A(1, 1, 1); STAGE_B(1, 0, 1); STAGE_B(1, 1, 1);
    asm volatile("s_waitcnt vmcnt(8)" ::: "memory");   // K0 complete
    __builtin_amdgcn_s_barrier();
    __builtin_amdgcn_sched_barrier(0);

#pragma unroll
    for (int i = 0; i < 6; ++i) {
        const int s0 = (2 * i) % 3, s1 = (2 * i + 1) % 3, s2 = (2 * i + 2) % 3;
        // ---- phase 0
        DSLOAD_A(s0, 0); DSLOAD_B(0);
        if (i < 5) STAGE_A(s2, 0, 2 * i + 2);
        BARRIER_IN(); MFMACL(0); BARRIER_OUT();
        // ---- phase 1
        DSLOAD_A(s0, 2);
        if (i < 5) STAGE_A(s2, 1, 2 * i + 2);
        BARRIER_IN(); MFMACL(2); BARRIER_OUT();
        // ---- phase 2
        DSLOAD_A(s0, 4);
        if (i < 5) STAGE_B(0, 0, 2 * i + 2);
        BARRIER_IN(); MFMACL(4); BARRIER_OUT();
        // ---- phase 3
        DSLOAD_A(s0, 6);
        if (i < 5) {
            STAGE_B(0, 1, 2 * i + 2);
            asm volatile("s_waitcnt vmcnt(8)" ::: "memory");
        } else {
            asm volatile("s_waitcnt vmcnt(0)" ::: "memory");
        }
        BARRIER_IN(); MFMACL(6); BARRIER_OUT();
        // ---- phase 4
        DSLOAD_A(s1, 0); DSLOAD_B(1);
        if (i < 5) STAGE_A(s0, 0, 2 * i + 3);
        BARRIER_IN(); MFMACL(0); BARRIER_OUT();
        // ---- phase 5
        DSLOAD_A(s1, 2);
        if (i < 5) STAGE_A(s0, 1, 2 * i + 3);
        BARRIER_IN(); MFMACL(2); BARRIER_OUT();
        // ---- phase 6
        DSLOAD_A(s1, 4);
        if (i < 5) STAGE_B(1, 0, 2 * i + 3);
        BARRIER_IN(); MFMACL(4); BARRIER_OUT();
        // ---- phase 7
        DSLOAD_A(s1, 6);
        if (i < 5) {
            STAGE_B(1, 1, 2 * i + 3);
            asm volatile("s_waitcnt vmcnt(8)" ::: "memory");
        }
        BARRIER_IN(); MFMACL(6); BARRIER_OUT();
    }

    // epilogue
    const int mat = (NMAT == 1) ? 0 : (n0g / DDIM);
    const int colbase = n0g - mat * DDIM + wcol;
    const float* bz = (mat == 0) ? bz0 : (mat == 1 ? bz1 : bz2);
    OutT* Cc = (mat == 0) ? Cz0 : (mat == 1 ? Cz1 : Cz2);
#pragma unroll
    for (int nf = 0; nf < 4; ++nf) {
        const int col = colbase + nf * 16 + lr;
        const float bb = bz[col];
#pragma unroll
        for (int mf = 0; mf < 8; ++mf) {
            const int row = m0 + wrow + mf * 16 + lg * 4;
#pragma unroll
            for (int r2 = 0; r2 < 4; ++r2)
                Cc[(size_t)(row + r2) * DDIM + col] = (OutT)(acc[mf][nf][r2] + bb);
        }
    }
#undef STAGE_A
#undef STAGE_B
#undef AF
#undef BF
#undef DSLOAD_A
#undef DSLOAD_B
#undef BARRIER_IN
#undef BARRIER_OUT
#undef MFMACL
}

// ---------------- fused attention, S^T layout, 8 waves per (b,h) -----------
__global__ __launch_bounds__(512, 2) void attn_kernel(const __bf16* __restrict__ Qg,
                                                      const __bf16* __restrict__ Kg,
                                                      const __bf16* __restrict__ Vg,
                                                      const __bf16* __restrict__ biasH,
                                                      __bf16* __restrict__ Og) {
    __shared__ __bf16 Ksm[208 * KSTR];
    __shared__ __bf16 Vts[64 * VSTR];
    __shared__ __bf16 Psm[8 * 16 * VSTR];

    const int b = blockIdx.x, h = blockIdx.y;
    const int tid = threadIdx.x, w = tid >> 6, l = tid & 63;
    const int lr = l & 15, lg = l >> 4;
    const size_t base = (size_t)(b * SEQ) * DDIM + h * 64;
    const __bf16* Kb = Kg + base;
    const __bf16* Vb = Vg + base;
    const __bf16* Qb = Qg + base;
    const __bf16* bh = biasH + (size_t)h * (SEQ * SEQ);

    for (int c = tid; c < SEQ * 8; c += 512) {
        int kk = c >> 3, d8 = (c & 7) << 3;
        *(bf16x8*)&Ksm[kk * KSTR + d8] = *(const bf16x8*)&Kb[(size_t)kk * DDIM + d8];
    }
    for (int c = tid; c < 12 * 9; c += 512) {
        int kk = SEQ + c / 9, d8 = (c % 9) * 8;
        *(uint4*)&Ksm[kk * KSTR + d8] = make_uint4(0u, 0u, 0u, 0u);
    }
    for (int c = tid; c < SEQ * 8; c += 512) {
        int kk = c >> 3, d8 = (c & 7) << 3;
        bf16x8 vv = *(const bf16x8*)&Vb[(size_t)kk * DDIM + d8];
#pragma unroll
        for (int j = 0; j < 8; ++j) Vts[(d8 + j) * VSTR + kk] = vv[j];
    }
    for (int c = tid; c < 64 * 28; c += 512)
        Vts[(c / 28) * VSTR + SEQ + (c % 28)] = (__bf16)0.f;
    __bf16* Pw = &Psm[w * 16 * VSTR];
    for (int c = l; c < 256; c += 64)
        Pw[(c >> 4) * VSTR + 208 + (c & 15)] = (__bf16)0.f;
    __syncthreads();

    for (int qt = w; qt < 13; qt += 8) {
        const int q0 = qt * 16;
        const int q = q0 + lr;
        const int qrow = min(q, SEQ - 1);
        bf16x8 bq0 = *(const bf16x8*)&Qb[(size_t)qrow * DDIM + lg * 8];
        bf16x8 bq1 = *(const bf16x8*)&Qb[(size_t)qrow * DDIM + 32 + lg * 8];

        f32x4 sc[13];
        __builtin_amdgcn_s_setprio(1);
#pragma unroll
        for (int t = 0; t < 13; ++t) {
            bf16x8 kf0 = *(const bf16x8*)&Ksm[(t * 16 + lr) * KSTR + lg * 8];
            bf16x8 kf1 = *(const bf16x8*)&Ksm[(t * 16 + lr) * KSTR + 32 + lg * 8];
            f32x4 a = {0.f, 0.f, 0.f, 0.f};
            a = MFMA(kf0, bq0, a);
            a = MFMA(kf1, bq1, a);
            sc[t] = a;
        }
        __builtin_amdgcn_s_setprio(0);

        float mx = -1e30f;
#pragma unroll
        for (int t = 0; t < 13; ++t) {
            const bool val4 = (t < 12) || (lg == 0);
            float bb[4] = {0.f, 0.f, 0.f, 0.f};
            if (val4) {
                bf16x4 b4 = *(const bf16x4*)&bh[(size_t)qrow * SEQ + t * 16 + lg * 4];
#pragma unroll
                for (int r = 0; r < 4; ++r) bb[r] = (float)b4[r];
            }
#pragma unroll
            for (int r = 0; r < 4; ++r) {
                float v = val4 ? (sc[t][r] * 0.125f + bb[r]) : -1e30f;
                sc[t][r] = v;
                mx = fmaxf(mx, v);
            }
        }
        mx = fmaxf(mx, __shfl_xor(mx, 16));
        mx = fmaxf(mx, __shfl_xor(mx, 32));

        float sum = 0.f;
#pragma unroll
        for (int t = 0; t < 13; ++t)
#pragma unroll
            for (int r = 0; r < 4; ++r) {
                float p = __expf(sc[t][r] - mx);
                sum += p;
                sc[t][r] = p;
            }
        sum += __shfl_xor(sum, 16);
        sum += __shfl_xor(sum, 32);
        const float inv = 1.f / sum;

#pragma unroll
        for (int t = 0; t < 13; ++t) {
            bf16x4 pk;
#pragma unroll
            for (int r = 0; r < 4; ++r) pk[r] = (__bf16)sc[t][r];
            *(bf16x4*)&Pw[lr * VSTR + t * 16 + lg * 4] = pk;
        }

        f32x4 oa[4];
#pragma unroll
        for (int i = 0; i < 4; ++i) oa[i] = (f32x4){0.f, 0.f, 0.f, 0.f};
        __builtin_amdgcn_s_setprio(1);
#pragma unroll
        for (int kt = 0; kt < 7; ++kt) {
            bf16x8 pf = *(const bf16x8*)&Pw[lr * VSTR + kt * 32 + lg * 8];
#pragma unroll
            for (int nt = 0; nt < 4; ++nt) {
                bf16x8 vf = *(const bf16x8*)&Vts[(nt * 16 + lr) * VSTR + kt * 32 + lg * 8];
                oa[nt] = MFMA(vf, pf, oa[nt]);
            }
        }
        __builtin_amdgcn_s_setprio(0);

        if (q < SEQ) {
#pragma unroll
            for (int nt = 0; nt < 4; ++nt) {
                bf16x4 ok;
#pragma unroll
                for (int r = 0; r < 4; ++r) ok[r] = (__bf16)(oa[nt][r] * inv);
                *(bf16x4*)&Og[(size_t)(b * SEQ + q) * DDIM + h * 64 + nt * 16 + lg * 4] = ok;
            }
        }
    }
}

// ---------------------------------------------------------------------------
extern "C" void kernel_launch(void* const* d_in, const int* in_sizes, int n_in,
                              void* d_out, int out_size, void* d_ws, size_t ws_size,
                              hipStream_t stream) {
    const float* x     = (const float*)d_in[0];
    const float* Wq    = (const float*)d_in[1];
    const float* bq    = (const float*)d_in[2];
    const float* Wk    = (const float*)d_in[3];
    const float* bk    = (const float*)d_in[4];
    const float* Wv    = (const float*)d_in[5];
    const float* bv    = (const float*)d_in[6];
    const float* Wo    = (const float*)d_in[7];
    const float* bo    = (const float*)d_in[8];
    const float* table = (const float*)d_in[9];
    const int*   rel   = (const int*)d_in[10];
    float* out = (float*)d_out;

    char* ws = (char*)d_ws;
    auto alloc = [&](size_t bytes) {
        char* p = ws;
        ws += (bytes + 255) & ~(size_t)255;
        return p;
    };
    const size_t mat = (size_t)MROWS * DDIM * sizeof(__bf16);
    __bf16* xb    = (__bf16*)alloc(mat);
    __bf16* Tqkv  = (__bf16*)alloc((size_t)3 * DDIM * DDIM * 2);   // stacked Wq^T,Wk^T,Wv^T
    __bf16* To    = (__bf16*)alloc((size_t)DDIM * DDIM * 2);
    __bf16* Qb    = (__bf16*)alloc(mat);
    __bf16* Kb    = (__bf16*)alloc(mat);
    __bf16* Vb    = (__bf16*)alloc(mat);
    __bf16* AO    = (__bf16*)alloc(mat);
    __bf16* biasH = (__bf16*)alloc((size_t)NHEAD * SEQ * SEQ * 2);

    f2b<<<dim3(4704), 256, 0, stream>>>(x, xb);
    wtrans<<<dim3(24, 24, 4), 256, 0, stream>>>(Wq, Wk, Wv, Wo,
                                                Tqkv, Tqkv + (size_t)DDIM * DDIM,
                                                Tqkv + (size_t)2 * DDIM * DDIM, To);
    bias_pre<<<dim3(1801), 256, 0, stream>>>(table, rel, biasH);

    // QKV: M=12544, N=2304 (stacked), K=768 -> 49*9 = 441 blocks
    gemm8p<__bf16, 3><<<dim3(441), 512, 0, stream>>>(xb, Tqkv, bq, bk, bv,
                                                     Qb, Kb, Vb, 9);
    attn_kernel<<<dim3(64, 12), 512, 0, stream>>>(Qb, Kb, Vb, biasH, AO);
    // O-proj: M=12544, N=768, K=768 -> 49*3 = 147 blocks, fp32 out
    gemm8p<float, 1><<<dim3(147), 512, 0, stream>>>(AO, To, bo, bo, bo,
                                                    out, out, out, 3);
}

// Round 5
// 160.221 us; speedup vs baseline: 1.2875x; 1.0725x over previous
//
#include <hip/hip_runtime.h>
#include <hip/hip_bf16.h>

// ---------------------------------------------------------------------------
// MultiHeadSelfAttention (Swin rel-pos bias), B=64 S=196 D=768 H=12 pd=64
// f2b ; wtrans(stacked) ; bias_pre(bf16) ; gemm8p QKV (256^2 8-phase) ;
// attn (S^T, chunked online softmax, no spill) ; gemm8p O-proj
// ---------------------------------------------------------------------------

typedef __bf16 bf16x8 __attribute__((ext_vector_type(8)));
typedef __bf16 bf16x4 __attribute__((ext_vector_type(4)));
typedef float  f32x4  __attribute__((ext_vector_type(4)));

#define MROWS 12544
#define DDIM  768
#define NHEAD 12
#define SEQ   196
#define KSTR  72
#define VSTR  232

static __device__ __forceinline__ f32x4 MFMA(bf16x8 a, bf16x8 b, f32x4 c) {
    return __builtin_amdgcn_mfma_f32_16x16x32_bf16(a, b, c, 0, 0, 0);
}

static __device__ __forceinline__ void gload16(const __bf16* g, __bf16* l) {
    __builtin_amdgcn_global_load_lds(
        (const __attribute__((address_space(1))) void*)(g),
        (__attribute__((address_space(3))) void*)(l),
        16, 0, 0);
}

// ---------------- prep: fp32 -> bf16 ---------------------------------------
__global__ __launch_bounds__(256) void f2b(const float* __restrict__ in,
                                           __bf16* __restrict__ out) {
    size_t i = ((size_t)blockIdx.x * 256 + threadIdx.x) * 8;
    f32x4 a = *(const f32x4*)&in[i];
    f32x4 b = *(const f32x4*)&in[i + 4];
    bf16x8 o;
    o[0] = (__bf16)a[0]; o[1] = (__bf16)a[1]; o[2] = (__bf16)a[2]; o[3] = (__bf16)a[3];
    o[4] = (__bf16)b[0]; o[5] = (__bf16)b[1]; o[6] = (__bf16)b[2]; o[7] = (__bf16)b[3];
    *(bf16x8*)&out[i] = o;
}

// ---------------- prep: W [k][n] fp32 -> Wt [n][k] bf16 --------------------
__global__ __launch_bounds__(256) void wtrans(const float* __restrict__ W0, const float* __restrict__ W1,
                                              const float* __restrict__ W2, const float* __restrict__ W3,
                                              __bf16* __restrict__ T0, __bf16* __restrict__ T1,
                                              __bf16* __restrict__ T2, __bf16* __restrict__ T3) {
    const float* Ws[4] = {W0, W1, W2, W3};
    __bf16*      Ts[4] = {T0, T1, T2, T3};
    const float* W = Ws[blockIdx.z];
    __bf16*      T = Ts[blockIdx.z];
    __shared__ __bf16 t[32][33];
    int k0 = blockIdx.x * 32, n0 = blockIdx.y * 32;
    int c = threadIdx.x & 31, r = threadIdx.x >> 5;
#pragma unroll
    for (int i = 0; i < 4; ++i)
        t[r + i * 8][c] = (__bf16)W[(size_t)(k0 + r + i * 8) * DDIM + n0 + c];
    __syncthreads();
#pragma unroll
    for (int i = 0; i < 4; ++i)
        T[(size_t)(n0 + r + i * 8) * DDIM + k0 + c] = t[c][r + i * 8];
}

// ---------------- prep: bias[h][q][k] = table[rel[q][k]][h]  (bf16) --------
__global__ __launch_bounds__(256) void bias_pre(const float* __restrict__ table,
                                                const int* __restrict__ rel,
                                                __bf16* __restrict__ biasH) {
    int i = blockIdx.x * 256 + threadIdx.x;
    if (i < NHEAD * SEQ * SEQ) {
        int h = i / (SEQ * SEQ), qk = i - h * (SEQ * SEQ);
        biasH[i] = (__bf16)table[rel[qk] * NHEAD + h];
    }
}

// ---------------------------------------------------------------------------
// 256x256 8-phase GEMM: C = A[M][768] * Bt[N][768]^T + bias
// ---------------------------------------------------------------------------
template <typename OutT, int NMAT>
__global__ __launch_bounds__(512, 2) void gemm8p(const __bf16* __restrict__ A,
                                                 const __bf16* __restrict__ Bt,
                                                 const float* __restrict__ bz0,
                                                 const float* __restrict__ bz1,
                                                 const float* __restrict__ bz2,
                                                 OutT* __restrict__ Cz0,
                                                 OutT* __restrict__ Cz1,
                                                 OutT* __restrict__ Cz2,
                                                 int nbn) {
    __shared__ __bf16 As[3][256 * 64];   // 3 x 32 KiB
    __shared__ __bf16 Bs[2][256 * 64];   // 2 x 32 KiB

    const int nwg = gridDim.x, orig = blockIdx.x;
    const int qq = nwg >> 3, r8 = nwg & 7, xcd = orig & 7, lin = orig >> 3;
    const int wg = (xcd < r8 ? xcd * (qq + 1) : r8 * (qq + 1) + (xcd - r8) * qq) + lin;
    const int bm = wg / nbn, bn = wg - bm * nbn;
    const int m0 = bm * 256, n0g = bn * 256;

    const int tid = threadIdx.x, w = tid >> 6, l = tid & 63;
    const int lr = l & 15, lg = l >> 4;
    const int wrow = (w >> 2) * 128;
    const int wcol = (w & 3) * 64;

    const int srow = w * 8 + (l >> 3);
    const int scol = ((l & 7) ^ ((l >> 3) & 7)) * 8;
    const __bf16* gA = A  + (size_t)(m0 + srow) * DDIM + scol;
    const __bf16* gB = Bt + (size_t)(n0g + srow) * DDIM + scol;

#define STAGE_A(slot, h, kt)                                                      \
    do {                                                                          \
        gload16(gA + ((h) * 128 + 0) * DDIM + (kt) * 64,                          \
                &As[slot][(h) * 8192 + 0 + w * 512]);                             \
        gload16(gA + ((h) * 128 + 64) * DDIM + (kt) * 64,                         \
                &As[slot][(h) * 8192 + 4096 + w * 512]);                          \
    } while (0)
#define STAGE_B(slot, h, kt)                                                      \
    do {                                                                          \
        gload16(gB + ((h) * 128 + 0) * DDIM + (kt) * 64,                          \
                &Bs[slot][(h) * 8192 + 0 + w * 512]);                             \
        gload16(gB + ((h) * 128 + 64) * DDIM + (kt) * 64,                         \
                &Bs[slot][(h) * 8192 + 4096 + w * 512]);                          \
    } while (0)

#define AF(slot, mf, ks)                                                          \
    (*(const bf16x8*)&As[slot][(w >> 2) * 8192 + ((mf) * 16 + lr) * 64 +          \
                              ((((ks) * 4 + lg) ^ (lr & 7))) * 8])
#define BF(slot, nf, ks)                                                          \
    (*(const bf16x8*)&Bs[slot][((w & 3) >> 1) * 8192 +                            \
                              ((w & 1) * 64 + (nf) * 16 + lr) * 64 +              \
                              ((((ks) * 4 + lg) ^ (lr & 7))) * 8])

    f32x4 acc[8][4];
#pragma unroll
    for (int i = 0; i < 8; ++i)
#pragma unroll
        for (int j = 0; j < 4; ++j) acc[i][j] = (f32x4){0.f, 0.f, 0.f, 0.f};

    bf16x8 a0, a1, a2, a3;
    bf16x8 bfr00, bfr01, bfr10, bfr11, bfr20, bfr21, bfr30, bfr31;

#define DSLOAD_A(slot, mf0)                                                       \
    a0 = AF(slot, mf0, 0); a1 = AF(slot, mf0, 1);                                 \
    a2 = AF(slot, (mf0) + 1, 0); a3 = AF(slot, (mf0) + 1, 1);
#define DSLOAD_B(slot)                                                            \
    bfr00 = BF(slot, 0, 0); bfr01 = BF(slot, 0, 1);                               \
    bfr10 = BF(slot, 1, 0); bfr11 = BF(slot, 1, 1);                               \
    bfr20 = BF(slot, 2, 0); bfr21 = BF(slot, 2, 1);                               \
    bfr30 = BF(slot, 3, 0); bfr31 = BF(slot, 3, 1);
#define BARRIER_IN()                                                              \
    __builtin_amdgcn_sched_barrier(0);                                            \
    __builtin_amdgcn_s_barrier();                                                 \
    asm volatile("s_waitcnt lgkmcnt(0)" ::: "memory");                            \
    __builtin_amdgcn_sched_barrier(0);                                            \
    __builtin_amdgcn_s_setprio(1);
#define BARRIER_OUT()                                                             \
    __builtin_amdgcn_s_setprio(0);                                                \
    __builtin_amdgcn_sched_barrier(0);                                            \
    __builtin_amdgcn_s_barrier();                                                 \
    __builtin_amdgcn_sched_barrier(0);
#define MFMACL(mf0)                                                               \
    acc[mf0][0] = MFMA(a0, bfr00, acc[mf0][0]);                                   \
    acc[mf0][0] = MFMA(a1, bfr01, acc[mf0][0]);                                   \
    acc[(mf0) + 1][0] = MFMA(a2, bfr00, acc[(mf0) + 1][0]);                       \
    acc[(mf0) + 1][0] = MFMA(a3, bfr01, acc[(mf0) + 1][0]);                       \
    acc[mf0][1] = MFMA(a0, bfr10, acc[mf0][1]);                                   \
    acc[mf0][1] = MFMA(a1, bfr11, acc[mf0][1]);                                   \
    acc[(mf0) + 1][1] = MFMA(a2, bfr10, acc[(mf0) + 1][1]);                       \
    acc[(mf0) + 1][1] = MFMA(a3, bfr11, acc[(mf0) + 1][1]);                       \
    acc[mf0][2] = MFMA(a0, bfr20, acc[mf0][2]);                                   \
    acc[mf0][2] = MFMA(a1, bfr21, acc[mf0][2]);                                   \
    acc[(mf0) + 1][2] = MFMA(a2, bfr20, acc[(mf0) + 1][2]);                       \
    acc[(mf0) + 1][2] = MFMA(a3, bfr21, acc[(mf0) + 1][2]);                       \
    acc[mf0][3] = MFMA(a0, bfr30, acc[mf0][3]);                                   \
    acc[mf0][3] = MFMA(a1, bfr31, acc[mf0][3]);                                   \
    acc[(mf0) + 1][3] = MFMA(a2, bfr30, acc[(mf0) + 1][3]);                       \
    acc[(mf0) + 1][3] = MFMA(a3, bfr31, acc[(mf0) + 1][3]);

    STAGE_A(0, 0, 0); STAGE_A(0, 1, 0); STAGE_B(0, 0, 0); STAGE_B(0, 1, 0);
    STAGE_A(1, 0, 1); STAGE_A(1, 1, 1); STAGE_B(1, 0, 1); STAGE_B(1, 1, 1);
    asm volatile("s_waitcnt vmcnt(8)" ::: "memory");
    __builtin_amdgcn_s_barrier();
    __builtin_amdgcn_sched_barrier(0);

#pragma unroll
    for (int i = 0; i < 6; ++i) {
        const int s0 = (2 * i) % 3, s1 = (2 * i + 1) % 3, s2 = (2 * i + 2) % 3;
        // ---- phase 0
        DSLOAD_A(s0, 0); DSLOAD_B(0);
        if (i < 5) STAGE_A(s2, 0, 2 * i + 2);
        BARRIER_IN(); MFMACL(0); BARRIER_OUT();
        // ---- phase 1
        DSLOAD_A(s0, 2);
        if (i < 5) STAGE_A(s2, 1, 2 * i + 2);
        BARRIER_IN(); MFMACL(2); BARRIER_OUT();
        // ---- phase 2
        DSLOAD_A(s0, 4);
        if (i < 5) STAGE_B(0, 0, 2 * i + 2);
        BARRIER_IN(); MFMACL(4); BARRIER_OUT();
        // ---- phase 3
        DSLOAD_A(s0, 6);
        if (i < 5) {
            STAGE_B(0, 1, 2 * i + 2);
            asm volatile("s_waitcnt vmcnt(8)" ::: "memory");
        } else {
            asm volatile("s_waitcnt vmcnt(0)" ::: "memory");
        }
        BARRIER_IN(); MFMACL(6); BARRIER_OUT();
        // ---- phase 4
        DSLOAD_A(s1, 0); DSLOAD_B(1);
        if (i < 5) STAGE_A(s0, 0, 2 * i + 3);
        BARRIER_IN(); MFMACL(0); BARRIER_OUT();
        // ---- phase 5
        DSLOAD_A(s1, 2);
        if (i < 5) STAGE_A(s0, 1, 2 * i + 3);
        BARRIER_IN(); MFMACL(2); BARRIER_OUT();
        // ---- phase 6
        DSLOAD_A(s1, 4);
        if (i < 5) STAGE_B(1, 0, 2 * i + 3);
        BARRIER_IN(); MFMACL(4); BARRIER_OUT();
        // ---- phase 7
        DSLOAD_A(s1, 6);
        if (i < 5) {
            STAGE_B(1, 1, 2 * i + 3);
            asm volatile("s_waitcnt vmcnt(8)" ::: "memory");
        }
        BARRIER_IN(); MFMACL(6); BARRIER_OUT();
    }

    const int mat = (NMAT == 1) ? 0 : (n0g / DDIM);
    const int colbase = n0g - mat * DDIM + wcol;
    const float* bz = (mat == 0) ? bz0 : (mat == 1 ? bz1 : bz2);
    OutT* Cc = (mat == 0) ? Cz0 : (mat == 1 ? Cz1 : Cz2);
#pragma unroll
    for (int nf = 0; nf < 4; ++nf) {
        const int col = colbase + nf * 16 + lr;
        const float bb = bz[col];
#pragma unroll
        for (int mf = 0; mf < 8; ++mf) {
            const int row = m0 + wrow + mf * 16 + lg * 4;
#pragma unroll
            for (int r2 = 0; r2 < 4; ++r2)
                Cc[(size_t)(row + r2) * DDIM + col] = (OutT)(acc[mf][nf][r2] + bb);
        }
    }
#undef STAGE_A
#undef STAGE_B
#undef AF
#undef BF
#undef DSLOAD_A
#undef DSLOAD_B
#undef BARRIER_IN
#undef BARRIER_OUT
#undef MFMACL
}

// ---------------- fused attention, S^T layout, chunked online softmax ------
// launch_bounds (512,1): relax VGPR cap (LDS already limits to 1 block/CU).
// Chunks keep live scores <= 8 f32x4 so even a 128-reg cap cannot spill.
__global__ __launch_bounds__(512, 1) void attn_kernel(const __bf16* __restrict__ Qg,
                                                      const __bf16* __restrict__ Kg,
                                                      const __bf16* __restrict__ Vg,
                                                      const __bf16* __restrict__ biasH,
                                                      __bf16* __restrict__ Og) {
    __shared__ __bf16 Ksm[208 * KSTR];
    __shared__ __bf16 Vts[64 * VSTR];
    __shared__ __bf16 Psm[8 * 16 * VSTR];

    const int b = blockIdx.x, h = blockIdx.y;
    const int tid = threadIdx.x, w = tid >> 6, l = tid & 63;
    const int lr = l & 15, lg = l >> 4;
    const size_t base = (size_t)(b * SEQ) * DDIM + h * 64;
    const __bf16* Kb = Kg + base;
    const __bf16* Vb = Vg + base;
    const __bf16* Qb = Qg + base;
    const __bf16* bh = biasH + (size_t)h * (SEQ * SEQ);

    for (int c = tid; c < SEQ * 8; c += 512) {
        int kk = c >> 3, d8 = (c & 7) << 3;
        *(bf16x8*)&Ksm[kk * KSTR + d8] = *(const bf16x8*)&Kb[(size_t)kk * DDIM + d8];
    }
    for (int c = tid; c < 12 * 9; c += 512) {
        int kk = SEQ + c / 9, d8 = (c % 9) * 8;
        *(uint4*)&Ksm[kk * KSTR + d8] = make_uint4(0u, 0u, 0u, 0u);
    }
    for (int c = tid; c < SEQ * 8; c += 512) {
        int kk = c >> 3, d8 = (c & 7) << 3;
        bf16x8 vv = *(const bf16x8*)&Vb[(size_t)kk * DDIM + d8];
#pragma unroll
        for (int j = 0; j < 8; ++j) Vts[(d8 + j) * VSTR + kk] = vv[j];
    }
    for (int c = tid; c < 64 * 28; c += 512)
        Vts[(c / 28) * VSTR + SEQ + (c % 28)] = (__bf16)0.f;
    __bf16* Pw = &Psm[w * 16 * VSTR];
    for (int c = l; c < 256; c += 64)
        Pw[(c >> 4) * VSTR + 208 + (c & 15)] = (__bf16)0.f;
    __syncthreads();

// chunk: tiles T0..T0+NTC-1 (QK^T+softmax chunk), PV over kt = KT0..KTN-1
#define CHUNK(T0, NTC, KT0, KTN)                                                  \
    {                                                                             \
        f32x4 sc[NTC];                                                            \
        __builtin_amdgcn_s_setprio(1);                                            \
        _Pragma("unroll")                                                         \
        for (int tt = 0; tt < NTC; ++tt) {                                        \
            const int t = (T0) + tt;                                              \
            bf16x8 kf0 = *(const bf16x8*)&Ksm[(t * 16 + lr) * KSTR + lg * 8];     \
            bf16x8 kf1 = *(const bf16x8*)&Ksm[(t * 16 + lr) * KSTR + 32 + lg * 8];\
            f32x4 a = {0.f, 0.f, 0.f, 0.f};                                       \
            a = MFMA(kf0, bq0, a);                                                \
            a = MFMA(kf1, bq1, a);                                                \
            sc[tt] = a;                                                           \
        }                                                                         \
        __builtin_amdgcn_s_setprio(0);                                            \
        float mc = -1e30f;                                                        \
        _Pragma("unroll")                                                         \
        for (int tt = 0; tt < NTC; ++tt) {                                        \
            const int t = (T0) + tt;                                              \
            const bool val4 = (t < 12) || (lg == 0);                              \
            float bb[4] = {0.f, 0.f, 0.f, 0.f};                                   \
            if (val4) {                                                           \
                bf16x4 b4 = *(const bf16x4*)&bh[(size_t)qrow * SEQ + t * 16 + lg * 4]; \
                _Pragma("unroll")                                                 \
                for (int r = 0; r < 4; ++r) bb[r] = (float)b4[r];                 \
            }                                                                     \
            _Pragma("unroll")                                                     \
            for (int r = 0; r < 4; ++r) {                                         \
                float v = val4 ? (sc[tt][r] * 0.125f + bb[r]) : -1e30f;           \
                sc[tt][r] = v;                                                    \
                mc = fmaxf(mc, v);                                                \
            }                                                                     \
        }                                                                         \
        mc = fmaxf(mc, __shfl_xor(mc, 16));                                       \
        mc = fmaxf(mc, __shfl_xor(mc, 32));                                       \
        const float mnew = fmaxf(m_run, mc);                                      \
        const float fsc = __expf(m_run - mnew);                                   \
        m_run = mnew;                                                             \
        s_run *= fsc;                                                             \
        _Pragma("unroll")                                                         \
        for (int i = 0; i < 4; ++i)                                               \
            _Pragma("unroll")                                                     \
            for (int r = 0; r < 4; ++r) oa[i][r] *= fsc;                          \
        float ps = 0.f;                                                           \
        _Pragma("unroll")                                                         \
        for (int tt = 0; tt < NTC; ++tt) {                                        \
            bf16x4 pk;                                                            \
            _Pragma("unroll")                                                     \
            for (int r = 0; r < 4; ++r) {                                         \
                float p = __expf(sc[tt][r] - m_run);                              \
                ps += p;                                                          \
                pk[r] = (__bf16)p;                                                \
            }                                                                     \
            *(bf16x4*)&Pw[lr * VSTR + ((T0) + tt) * 16 + lg * 4] = pk;            \
        }                                                                         \
        ps += __shfl_xor(ps, 16);                                                 \
        ps += __shfl_xor(ps, 32);                                                 \
        s_run += ps;                                                              \
        __builtin_amdgcn_s_setprio(1);                                            \
        _Pragma("unroll")                                                         \
        for (int kt = (KT0); kt < (KTN); ++kt) {                                  \
            bf16x8 pf = *(const bf16x8*)&Pw[lr * VSTR + kt * 32 + lg * 8];        \
            _Pragma("unroll")                                                     \
            for (int nt = 0; nt < 4; ++nt) {                                      \
                bf16x8 vf = *(const bf16x8*)&Vts[(nt * 16 + lr) * VSTR + kt * 32 + lg * 8]; \
                oa[nt] = MFMA(vf, pf, oa[nt]);                                    \
            }                                                                     \
        }                                                                         \
        __builtin_amdgcn_s_setprio(0);                                            \
    }

    for (int qt = w; qt < 13; qt += 8) {
        const int q0 = qt * 16;
        const int q = q0 + lr;
        const int qrow = min(q, SEQ - 1);
        bf16x8 bq0 = *(const bf16x8*)&Qb[(size_t)qrow * DDIM + lg * 8];
        bf16x8 bq1 = *(const bf16x8*)&Qb[(size_t)qrow * DDIM + 32 + lg * 8];

        float m_run = -1e30f, s_run = 0.f;
        f32x4 oa[4];
#pragma unroll
        for (int i = 0; i < 4; ++i) oa[i] = (f32x4){0.f, 0.f, 0.f, 0.f};

        CHUNK(0, 8, 0, 4);     // tiles 0..7   -> P cols 0..127,  PV kt 0..3
        CHUNK(8, 5, 4, 7);     // tiles 8..12  -> P cols 128..207, PV kt 4..6 (pad zeroed)

        const float inv = 1.f / s_run;
        if (q < SEQ) {
#pragma unroll
            for (int nt = 0; nt < 4; ++nt) {
                bf16x4 ok;
#pragma unroll
                for (int r = 0; r < 4; ++r) ok[r] = (__bf16)(oa[nt][r] * inv);
                *(bf16x4*)&Og[(size_t)(b * SEQ + q) * DDIM + h * 64 + nt * 16 + lg * 4] = ok;
            }
        }
    }
#undef CHUNK
}

// ---------------------------------------------------------------------------
extern "C" void kernel_launch(void* const* d_in, const int* in_sizes, int n_in,
                              void* d_out, int out_size, void* d_ws, size_t ws_size,
                              hipStream_t stream) {
    const float* x     = (const float*)d_in[0];
    const float* Wq    = (const float*)d_in[1];
    const float* bq    = (const float*)d_in[2];
    const float* Wk    = (const float*)d_in[3];
    const float* bk    = (const float*)d_in[4];
    const float* Wv    = (const float*)d_in[5];
    const float* bv    = (const float*)d_in[6];
    const float* Wo    = (const float*)d_in[7];
    const float* bo    = (const float*)d_in[8];
    const float* table = (const float*)d_in[9];
    const int*   rel   = (const int*)d_in[10];
    float* out = (float*)d_out;

    char* ws = (char*)d_ws;
    auto alloc = [&](size_t bytes) {
        char* p = ws;
        ws += (bytes + 255) & ~(size_t)255;
        return p;
    };
    const size_t mat = (size_t)MROWS * DDIM * sizeof(__bf16);
    __bf16* xb    = (__bf16*)alloc(mat);
    __bf16* Tqkv  = (__bf16*)alloc((size_t)3 * DDIM * DDIM * 2);
    __bf16* To    = (__bf16*)alloc((size_t)DDIM * DDIM * 2);
    __bf16* Qb    = (__bf16*)alloc(mat);
    __bf16* Kb    = (__bf16*)alloc(mat);
    __bf16* Vb    = (__bf16*)alloc(mat);
    __bf16* AO    = (__bf16*)alloc(mat);
    __bf16* biasH = (__bf16*)alloc((size_t)NHEAD * SEQ * SEQ * 2);

    f2b<<<dim3(4704), 256, 0, stream>>>(x, xb);
    wtrans<<<dim3(24, 24, 4), 256, 0, stream>>>(Wq, Wk, Wv, Wo,
                                                Tqkv, Tqkv + (size_t)DDIM * DDIM,
                                                Tqkv + (size_t)2 * DDIM * DDIM, To);
    bias_pre<<<dim3(1801), 256, 0, stream>>>(table, rel, biasH);

    gemm8p<__bf16, 3><<<dim3(441), 512, 0, stream>>>(xb, Tqkv, bq, bk, bv,
                                                     Qb, Kb, Vb, 9);
    attn_kernel<<<dim3(64, 12), 512, 0, stream>>>(Qb, Kb, Vb, biasH, AO);
    gemm8p<float, 1><<<dim3(147), 512, 0, stream>>>(AO, To, bo, bo, bo,
                                                    out, out, out, 3);
}